// Round 1
// baseline (1131.532 us; speedup 1.0000x reference)
//
#include <hip/hip_runtime.h>

typedef unsigned short u16;
typedef __attribute__((ext_vector_type(8))) short bf16x8;
typedef __attribute__((ext_vector_type(4))) float f32x4;
typedef __attribute__((ext_vector_type(4))) int i32x4;

#define DEV __device__ __forceinline__

DEV u16 f2bf(float f){
  unsigned u = __float_as_uint(f);
  u += 0x7fffu + ((u >> 16) & 1u);
  return (u16)(u >> 16);
}

// Inverse spiral map: pixel index (0..80) -> spiral token position (0..80).
// Ring r starts at 1+4r(r-1); segments: top row, right col, bottom row, left col.
DEV int spiral_t(int pix){
  int px = pix / 9, py = pix % 9;
  int dr = px - 4, dc = py - 4;
  int ar = dr < 0 ? -dr : dr, ac = dc < 0 ? -dc : dc;
  int r = ar > ac ? ar : ac;
  if (r == 0) return 0;
  int start = 1 + 4*r*(r-1);
  if (dr == -r && dc >= -r+1) return start + dc + r - 1;
  if (dc == r)  return start + 2*r + dr + r - 1;
  if (dr == r)  return start + 4*r + dc + r;
  return start + 6*r + dr + r;
}

// ---------------- weight transpose: w2c[64][240][3][3] -> Wt2[72 tiles][64 o][32 k] bf16, BN scale folded
__global__ __launch_bounds__(256) void k_wt(const float* __restrict__ w2c,
                                            const float* __restrict__ g2,
                                            const float* __restrict__ v2,
                                            u16* __restrict__ Wt2){
  int idx = blockIdx.x*256 + threadIdx.x;
  if (idx >= 72*64*32) return;
  int kk = idx & 31;
  int o  = (idx >> 5) & 63;
  int tile = idx >> 11;          // 0..71
  int dxy = tile >> 3;           // 0..8
  int chunk = tile & 7;          // 0..7
  int ch = chunk*32 + kk;        // padded channel
  float v = 0.f;
  if (ch < 240){
    float s2 = g2[o] * rsqrtf(v2[o] + 1e-5f);
    v = w2c[(o*240 + ch)*9 + dxy] * s2;
  }
  Wt2[idx] = f2bf(v);
}

// ---------------- conv3d (1->8, k=3^3, SAME) + BN + ReLU -> h1 bf16 [B][81][240], ch = co*30+dd
__global__ __launch_bounds__(256) void k_conv3d(const float* __restrict__ x,
    const float* __restrict__ w3, const float* __restrict__ b3,
    const float* __restrict__ g3, const float* __restrict__ be3,
    const float* __restrict__ m3, const float* __restrict__ v3,
    u16* __restrict__ h1){
  __shared__ float tile[2430];
  __shared__ float wle[216];
  __shared__ float sc[8], sh[8];
  int b = blockIdx.x, tid = threadIdx.x;
  const float* xin = x + b*2430;
  for (int i = tid; i < 2430; i += 256) tile[i] = xin[i];
  if (tid < 216) wle[tid] = w3[tid];
  if (tid < 8){
    float s = g3[tid]*rsqrtf(v3[tid]+1e-5f);
    sc[tid] = s;
    sh[tid] = (b3[tid]-m3[tid])*s + be3[tid];
  }
  __syncthreads();
  for (int i = tid; i < 19440; i += 256){
    int ch = i % 240, pix = i / 240;
    int co = ch / 30, dd = ch % 30;
    int px = pix / 9, py = pix % 9;
    float acc = 0.f;
    const float* wp = wle + co*27;
    #pragma unroll
    for (int kd=0; kd<3; kd++){
      int d2 = dd + kd - 1; if ((unsigned)d2 >= 30u) continue;
      #pragma unroll
      for (int kx=0; kx<3; kx++){
        int x2 = px + kx - 1; if ((unsigned)x2 >= 9u) continue;
        #pragma unroll
        for (int ky=0; ky<3; ky++){
          int y2 = py + ky - 1; if ((unsigned)y2 >= 9u) continue;
          acc += tile[(d2*9 + x2)*9 + y2] * wp[(kd*3+kx)*3+ky];
        }
      }
    }
    float val = fmaxf(acc*sc[co] + sh[co], 0.f);
    h1[b*19440 + i] = f2bf(val);
  }
}

// ---------------- conv2d as MFMA GEMM: [M=331776, K=2304pad] x [K, 64] + BN bias + ReLU + spiral scatter + pos_emb
__global__ __launch_bounds__(256) void k_conv2d(const u16* __restrict__ h1,
    const u16* __restrict__ Wt2,
    const float* __restrict__ b2c, const float* __restrict__ g2,
    const float* __restrict__ be2, const float* __restrict__ m2,
    const float* __restrict__ v2,
    const float* __restrict__ pos_emb, float* __restrict__ stok){
  __shared__ i32x4 AlV[640];   // 128 rows x 80B (40 ushorts) -- stride 80B => <=2-way bank aliasing
  __shared__ i32x4 BlV[320];   // 64 rows x 80B
  int tid = threadIdx.x;
  int bm = blockIdx.x;

  // staging ids: 2 threads per A-row, 32B each
  int r = tid >> 1, hh = tid & 1;
  int gm = bm*128 + r;
  unsigned bA = (unsigned)gm / 81u;
  unsigned pixA = (unsigned)gm % 81u;
  int px = (int)pixA / 9, py = (int)pixA % 9;
  const u16* h1b = h1 + (size_t)bA*19440;

  int wv = tid >> 6, ln = tid & 63;
  int lq = ln >> 4, lr = ln & 15;

  f32x4 acc[2][4];
  #pragma unroll
  for (int i=0;i<2;i++)
    #pragma unroll
    for (int j=0;j<4;j++) acc[i][j] = (f32x4){0.f,0.f,0.f,0.f};

  for (int dxy = 0; dxy < 9; dxy++){
    int dx = dxy/3 - 1, dy = dxy%3 - 1;
    int px2 = px + dx, py2 = py + dy;
    bool pv = (px2>=0 && px2<9 && py2>=0 && py2<9);
    const u16* arow = h1b + (px2*9+py2)*240;
    for (int chunk = 0; chunk < 8; chunk++){
      int ch0 = chunk*32 + hh*16;
      __syncthreads();   // protect LDS from previous iter's readers
      // stage A (16 bf16 = 32B per thread)
      i32x4 a0 = (i32x4){0,0,0,0}, a1 = (i32x4){0,0,0,0};
      if (pv && ch0 < 240){
        const i32x4* src = (const i32x4*)(arow + ch0);
        a0 = src[0]; a1 = src[1];
      }
      i32x4* adst = (i32x4*)((char*)AlV + r*80 + hh*32);
      adst[0] = a0; adst[1] = a1;
      // stage B (16B per thread), Wt2 tile is [64 o][32 k]
      {
        int tI = dxy*8 + chunk;
        i32x4 wv4 = ((const i32x4*)(Wt2 + tI*2048))[tid];
        int o = tid >> 2, q = tid & 3;
        *(i32x4*)((char*)BlV + o*80 + q*16) = wv4;
      }
      __syncthreads();
      // fragments
      bf16x8 afr[2], bfr[4];
      #pragma unroll
      for (int i=0;i<2;i++){
        int row = (wv*2+i)*16 + lr;
        afr[i] = *(const bf16x8*)((const char*)AlV + row*80 + lq*16);
      }
      #pragma unroll
      for (int j=0;j<4;j++){
        int orow = j*16 + lr;
        bfr[j] = *(const bf16x8*)((const char*)BlV + orow*80 + lq*16);
      }
      #pragma unroll
      for (int i=0;i<2;i++)
        #pragma unroll
        for (int j=0;j<4;j++)
          acc[i][j] = __builtin_amdgcn_mfma_f32_16x16x32_bf16(afr[i], bfr[j], acc[i][j], 0, 0, 0);
    }
  }

  // epilogue: bias (BN folded) + ReLU + spiral scatter + pos_emb
  float t2c[4];
  #pragma unroll
  for (int j=0;j<4;j++){
    int col = j*16 + lr;
    float s2 = g2[col]*rsqrtf(v2[col]+1e-5f);
    t2c[j] = (b2c[col]-m2[col])*s2 + be2[col];
  }
  #pragma unroll
  for (int i=0;i<2;i++){
    #pragma unroll
    for (int e=0;e<4;e++){
      int row = (wv*2+i)*16 + lq*4 + e;
      int gm2 = bm*128 + row;
      unsigned b2 = (unsigned)gm2 / 81u;
      unsigned pix2 = (unsigned)gm2 % 81u;
      int tsp = spiral_t((int)pix2);
      float* dst = stok + ((size_t)b2*81 + tsp)*64;
      const float* pe = pos_emb + (1+tsp)*64;
      #pragma unroll
      for (int j=0;j<4;j++){
        int col = j*16 + lr;
        dst[col] = fmaxf(acc[i][j][e] + t2c[j], 0.f) + pe[col];
      }
    }
  }
}

// ---------------- token mixer: LN1, B/C/delta matmuls, SToken, S6 scan, pool, LN2+MLP
__global__ __launch_bounds__(256) void k_token(const float* __restrict__ stok,
    const float* __restrict__ pos_emb, const float* __restrict__ cls_tok,
    const float* __restrict__ ln1_g, const float* __restrict__ ln1_b,
    const float* __restrict__ Wb, const float* __restrict__ bb,
    const float* __restrict__ Wc, const float* __restrict__ bc,
    const float* __restrict__ Wd, const float* __restrict__ bd,
    const float* __restrict__ delta_p, const float* __restrict__ A_p,
    const float* __restrict__ Wst, const float* __restrict__ bst,
    const float* __restrict__ bias_st,
    const float* __restrict__ ln2_g, const float* __restrict__ ln2_b,
    const float* __restrict__ Wm1, const float* __restrict__ bm1,
    const float* __restrict__ Wm2, const float* __restrict__ bm2,
    float* __restrict__ out){
  __shared__ float xnL[84*64];
  __shared__ float B0L[84*64];
  __shared__ float CL [84*64];
  __shared__ float DL [84*64];
  __shared__ float WbL[4096], WcL[4096], WdL[4096];
  __shared__ float tsum[64], xsum[64], sqsL[64], ynL[64], hbL[64];
  __shared__ float pt[2][4][64];

  int b = blockIdx.x, tid = threadIdx.x;
  int wv = tid >> 6, d = tid & 63;

  for (int i = tid; i < 4096; i += 256){ WbL[i]=Wb[i]; WcL[i]=Wc[i]; WdL[i]=Wd[i]; }

  const float* sb = stok + (size_t)b*81*64;
  float lg = ln1_g[d], lb = ln1_b[d];
  float ptok = 0.f, pxn = 0.f;
  // phase 1: LN per token (one wave per token), accumulate tok-sum and xn-sum
  for (int t = wv; t < 82; t += 4){
    float xv = (t==0) ? (cls_tok[d] + pos_emb[d]) : sb[(t-1)*64 + d];
    float s1 = xv, s2v = xv*xv;
    #pragma unroll
    for (int off=32; off>0; off>>=1){ s1 += __shfl_xor(s1, off, 64); s2v += __shfl_xor(s2v, off, 64); }
    float mean = s1 * (1.f/64.f);
    float var  = s2v*(1.f/64.f) - mean*mean;
    float xn = (xv - mean) * rsqrtf(var + 1e-5f) * lg + lb;
    xnL[t*64+d] = xn;
    ptok += xv; pxn += xn;
  }
  pt[0][wv][d] = ptok; pt[1][wv][d] = pxn;
  __syncthreads();
  if (tid < 64){
    tsum[d] = pt[0][0][d]+pt[0][1][d]+pt[0][2][d]+pt[0][3][d];
    xsum[d] = (pt[1][0][d]+pt[1][1][d]+pt[1][2][d]+pt[1][3][d]) * (1.f/82.f); // sq0
    xnL[82*64 + d] = 0.f;   // zero row for padded reads
    xnL[83*64 + d] = 0.f;
  }
  __syncthreads();

  // phase 2: B0 = xn@Wb+bb, C = xn@Wc+bc, delta = sigmoid(xn@Wd+bd+delta_p). 21 tokens/wave, unroll 4.
  int t0 = wv*21;
  for (int ti = 0; ti < 21; ti += 4){
    int ta[4]; float aB[4], aC[4], aD[4];
    #pragma unroll
    for (int u=0;u<4;u++){
      int tt = t0 + ti + u;
      bool va = (ti+u < 21) && (tt < 82);
      ta[u] = va ? tt : 82;
      aB[u] = bb[d]; aC[u] = bc[d];
      aD[u] = bd[d] + (va ? delta_p[tt*64 + d] : 0.f);
    }
    for (int k = 0; k < 64; k++){
      float w1 = WbL[k*64+d], w2 = WcL[k*64+d], w3v = WdL[k*64+d];
      #pragma unroll
      for (int u=0;u<4;u++){
        float xk = xnL[ta[u]*64 + k];
        aB[u] = fmaf(xk, w1, aB[u]);
        aC[u] = fmaf(xk, w2, aC[u]);
        aD[u] = fmaf(xk, w3v, aD[u]);
      }
    }
    #pragma unroll
    for (int u=0;u<4;u++){
      if (ta[u] < 82){
        int tt = ta[u];
        B0L[tt*64+d] = aB[u];
        CL [tt*64+d] = aC[u];
        DL [tt*64+d] = 1.f/(1.f + __expf(-aD[u]));
      }
    }
  }
  __syncthreads();

  // phase 2b: SToken squeeze: sqs = sigmoid(relu(sq0@Wst+bst)) + bias_st
  if (tid < 64){
    float a = bst[d];
    for (int k=0;k<64;k++) a = fmaf(xsum[k], Wst[k*64+d], a);
    a = fmaxf(a, 0.f);
    a = 1.f/(1.f + __expf(-a));
    sqsL[d] = a + bias_st[d];
  }
  __syncthreads();

  // phase 3: sequential S6 scan + pooled + LN2 (single wave, lane = dim)
  float pooled = 0.f;
  if (tid < 64){
    float s = 0.f, racc = 0.f, sqs = sqsL[d];
    for (int t = 0; t < 82; t++){
      float xv = xnL[t*64+d];
      float dl = DL[t*64+d];
      float a  = dl * A_p[t*64+d];
      float bx = dl * B0L[t*64+d] * xv;
      s = fmaf(a, s, bx);
      float o = fmaf(CL[t*64+d], s, sqs*xv);
      float z = 1.f/(1.f + __expf(-xv));
      racc = fmaf(o, z, racc);
    }
    pooled = (tsum[d] + racc) * (1.f/82.f);
    float s1 = pooled, s2v = pooled*pooled;
    #pragma unroll
    for (int off=32; off>0; off>>=1){ s1 += __shfl_xor(s1, off, 64); s2v += __shfl_xor(s2v, off, 64); }
    float mean = s1*(1.f/64.f), var = s2v*(1.f/64.f) - mean*mean;
    ynL[d] = (pooled - mean)*rsqrtf(var + 1e-5f)*ln2_g[d] + ln2_b[d];
  }
  __syncthreads();
  if (tid < 64){
    float a = bm1[d];
    for (int k=0;k<64;k++) a = fmaf(ynL[k], Wm1[k*64+d], a);
    hbL[d] = 0.5f*a*(1.f + erff(a*0.70710678118654752f));   // exact GELU
  }
  __syncthreads();
  if (tid < 64){
    float a = bm2[d];
    for (int k=0;k<64;k++) a = fmaf(hbL[k], Wm2[k*64+d], a);
    out[b*64 + d] = pooled + a;
  }
}

extern "C" void kernel_launch(void* const* d_in, const int* in_sizes, int n_in,
                              void* d_out, int out_size, void* d_ws, size_t ws_size,
                              hipStream_t stream){
  const float* x       = (const float*)d_in[0];
  const float* w3      = (const float*)d_in[1];
  const float* b3      = (const float*)d_in[2];
  const float* g3      = (const float*)d_in[3];
  const float* be3     = (const float*)d_in[4];
  const float* m3      = (const float*)d_in[5];
  const float* v3      = (const float*)d_in[6];
  const float* w2c     = (const float*)d_in[7];
  const float* b2c     = (const float*)d_in[8];
  const float* g2      = (const float*)d_in[9];
  const float* be2     = (const float*)d_in[10];
  const float* m2      = (const float*)d_in[11];
  const float* v2      = (const float*)d_in[12];
  const float* pos_emb = (const float*)d_in[13];
  const float* cls_tok = (const float*)d_in[14];
  const float* ln1_g   = (const float*)d_in[15];
  const float* ln1_b   = (const float*)d_in[16];
  const float* Wb      = (const float*)d_in[17];
  const float* bbv     = (const float*)d_in[18];
  const float* Wc      = (const float*)d_in[19];
  const float* bc      = (const float*)d_in[20];
  const float* Wd      = (const float*)d_in[21];
  const float* bd      = (const float*)d_in[22];
  const float* delta_p = (const float*)d_in[23];
  const float* A_p     = (const float*)d_in[24];
  const float* Wst     = (const float*)d_in[25];
  const float* bst     = (const float*)d_in[26];
  const float* bias_st = (const float*)d_in[27];
  const float* ln2_g   = (const float*)d_in[28];
  const float* ln2_b   = (const float*)d_in[29];
  const float* Wm1     = (const float*)d_in[30];
  const float* bm1     = (const float*)d_in[31];
  const float* Wm2     = (const float*)d_in[32];
  const float* bm2     = (const float*)d_in[33];

  // workspace layout
  u16*   h1   = (u16*)d_ws;                                   // 4096*81*240 bf16 = 159,252,480 B
  u16*   Wt2  = (u16*)((char*)d_ws + 159252480);              // 72*64*32 bf16   =     294,912 B
  float* stok = (float*)((char*)d_ws + 159547392);            // 4096*81*64 f32  =  84,934,656 B

  k_wt    <<<576,  256, 0, stream>>>(w2c, g2, v2, Wt2);
  k_conv3d<<<4096, 256, 0, stream>>>(x, w3, b3, g3, be3, m3, v3, h1);
  k_conv2d<<<2592, 256, 0, stream>>>(h1, Wt2, b2c, g2, be2, m2, v2, pos_emb, stok);
  k_token <<<4096, 256, 0, stream>>>(stok, pos_emb, cls_tok, ln1_g, ln1_b,
                                     Wb, bbv, Wc, bc, Wd, bd, delta_p, A_p,
                                     Wst, bst, bias_st, ln2_g, ln2_b,
                                     Wm1, bm1, Wm2, bm2, (float*)d_out);
}

// Round 3
// 664.123 us; speedup vs baseline: 1.7038x; 1.7038x over previous
//
#include <hip/hip_runtime.h>

typedef unsigned short u16;
typedef __attribute__((ext_vector_type(8))) short bf16x8;
typedef __attribute__((ext_vector_type(4))) float f32x4;
typedef __attribute__((ext_vector_type(4))) int i32x4;

#define DEV __device__ __forceinline__

DEV u16 f2bf(float f){
  unsigned u = __float_as_uint(f);
  u += 0x7fffu + ((u >> 16) & 1u);
  return (u16)(u >> 16);
}
DEV float bf2f(u16 h){ return __uint_as_float(((unsigned)h) << 16); }

// Inverse spiral map: pixel index (0..80) -> spiral token position (0..80).
DEV int spiral_t(int pix){
  int px = pix / 9, py = pix % 9;
  int dr = px - 4, dc = py - 4;
  int ar = dr < 0 ? -dr : dr, ac = dc < 0 ? -dc : dc;
  int r = ar > ac ? ar : ac;
  if (r == 0) return 0;
  int start = 1 + 4*r*(r-1);
  if (dr == -r && dc >= -r+1) return start + dc + r - 1;
  if (dc == r)  return start + 2*r + dr + r - 1;
  if (dr == r)  return start + 4*r + dc + r;
  return start + 6*r + dr + r;
}

// ---------------- weight prep: Wt2 (conv2d tiles, BN folded)
__global__ __launch_bounds__(256) void k_wt(const float* __restrict__ w2c,
                                            const float* __restrict__ g2,
                                            const float* __restrict__ v2,
                                            u16* __restrict__ Wt2){
  int idx = blockIdx.x*256 + threadIdx.x;
  if (idx >= 72*64*32) return;
  int kk = idx & 31;
  int o  = (idx >> 5) & 63;
  int tile = idx >> 11;          // 0..71
  int dxy = tile >> 3;           // 0..8
  int chunk = tile & 7;          // 0..7
  int ch = chunk*32 + kk;        // padded channel
  float v = 0.f;
  if (ch < 240){
    float s2 = g2[o] * rsqrtf(v2[o] + 1e-5f);
    v = w2c[(o*240 + ch)*9 + dxy] * s2;
  }
  Wt2[idx] = f2bf(v);
}

// ---------------- conv3d (1->8, k=3^3, SAME) + BN + ReLU -> h1 bf16 [B][81][240]
__global__ __launch_bounds__(256) void k_conv3d(const float* __restrict__ x,
    const float* __restrict__ w3, const float* __restrict__ b3,
    const float* __restrict__ g3, const float* __restrict__ be3,
    const float* __restrict__ m3, const float* __restrict__ v3,
    u16* __restrict__ h1){
  __shared__ float tile[2430];
  __shared__ float wle[216];
  __shared__ float sc[8], sh[8];
  int b = blockIdx.x, tid = threadIdx.x;
  const float* xin = x + b*2430;
  for (int i = tid; i < 2430; i += 256) tile[i] = xin[i];
  if (tid < 216) wle[tid] = w3[tid];
  if (tid < 8){
    float s = g3[tid]*rsqrtf(v3[tid]+1e-5f);
    sc[tid] = s;
    sh[tid] = (b3[tid]-m3[tid])*s + be3[tid];
  }
  __syncthreads();
  for (int i = tid; i < 19440; i += 256){
    int ch = i % 240, pix = i / 240;
    int co = ch / 30, dd = ch % 30;
    int px = pix / 9, py = pix % 9;
    float acc = 0.f;
    const float* wp = wle + co*27;
    #pragma unroll
    for (int kd=0; kd<3; kd++){
      int d2 = dd + kd - 1; if ((unsigned)d2 >= 30u) continue;
      #pragma unroll
      for (int kx=0; kx<3; kx++){
        int x2 = px + kx - 1; if ((unsigned)x2 >= 9u) continue;
        #pragma unroll
        for (int ky=0; ky<3; ky++){
          int y2 = py + ky - 1; if ((unsigned)y2 >= 9u) continue;
          acc += tile[(d2*9 + x2)*9 + y2] * wp[(kd*3+kx)*3+ky];
        }
      }
    }
    float val = fmaxf(acc*sc[co] + sh[co], 0.f);
    h1[b*19440 + i] = f2bf(val);
  }
}

// ---------------- conv2d as MFMA GEMM + BN + ReLU + spiral scatter + pos_emb
__global__ __launch_bounds__(256) void k_conv2d(const u16* __restrict__ h1,
    const u16* __restrict__ Wt2,
    const float* __restrict__ b2c, const float* __restrict__ g2,
    const float* __restrict__ be2, const float* __restrict__ m2,
    const float* __restrict__ v2,
    const float* __restrict__ pos_emb, float* __restrict__ stok){
  __shared__ i32x4 AlV[640];   // 128 rows x 80B
  __shared__ i32x4 BlV[320];   // 64 rows x 80B
  int tid = threadIdx.x;
  int bm = blockIdx.x;

  int r = tid >> 1, hh = tid & 1;
  int gm = bm*128 + r;
  unsigned bA = (unsigned)gm / 81u;
  unsigned pixA = (unsigned)gm % 81u;
  int px = (int)pixA / 9, py = (int)pixA % 9;
  const u16* h1b = h1 + (size_t)bA*19440;

  int wv = tid >> 6, ln = tid & 63;
  int lq = ln >> 4, lr = ln & 15;

  f32x4 acc[2][4];
  #pragma unroll
  for (int i=0;i<2;i++)
    #pragma unroll
    for (int j=0;j<4;j++) acc[i][j] = (f32x4){0.f,0.f,0.f,0.f};

  for (int dxy = 0; dxy < 9; dxy++){
    int dx = dxy/3 - 1, dy = dxy%3 - 1;
    int px2 = px + dx, py2 = py + dy;
    bool pv = (px2>=0 && px2<9 && py2>=0 && py2<9);
    const u16* arow = h1b + (px2*9+py2)*240;
    for (int chunk = 0; chunk < 8; chunk++){
      int ch0 = chunk*32 + hh*16;
      __syncthreads();
      i32x4 a0 = (i32x4){0,0,0,0}, a1 = (i32x4){0,0,0,0};
      if (pv && ch0 < 240){
        const i32x4* src = (const i32x4*)(arow + ch0);
        a0 = src[0]; a1 = src[1];
      }
      i32x4* adst = (i32x4*)((char*)AlV + r*80 + hh*32);
      adst[0] = a0; adst[1] = a1;
      {
        int tI = dxy*8 + chunk;
        i32x4 wv4 = ((const i32x4*)(Wt2 + tI*2048))[tid];
        int o = tid >> 2, q = tid & 3;
        *(i32x4*)((char*)BlV + o*80 + q*16) = wv4;
      }
      __syncthreads();
      bf16x8 afr[2], bfr[4];
      #pragma unroll
      for (int i=0;i<2;i++){
        int row = (wv*2+i)*16 + lr;
        afr[i] = *(const bf16x8*)((const char*)AlV + row*80 + lq*16);
      }
      #pragma unroll
      for (int j=0;j<4;j++){
        int orow = j*16 + lr;
        bfr[j] = *(const bf16x8*)((const char*)BlV + orow*80 + lq*16);
      }
      #pragma unroll
      for (int i=0;i<2;i++)
        #pragma unroll
        for (int j=0;j<4;j++)
          acc[i][j] = __builtin_amdgcn_mfma_f32_16x16x32_bf16(afr[i], bfr[j], acc[i][j], 0, 0, 0);
    }
  }

  float t2c[4];
  #pragma unroll
  for (int j=0;j<4;j++){
    int col = j*16 + lr;
    float s2 = g2[col]*rsqrtf(v2[col]+1e-5f);
    t2c[j] = (b2c[col]-m2[col])*s2 + be2[col];
  }
  #pragma unroll
  for (int i=0;i<2;i++){
    #pragma unroll
    for (int e=0;e<4;e++){
      int row = (wv*2+i)*16 + lq*4 + e;
      int gm2 = bm*128 + row;
      unsigned b2 = (unsigned)gm2 / 81u;
      unsigned pix2 = (unsigned)gm2 % 81u;
      int tsp = spiral_t((int)pix2);
      float* dst = stok + ((size_t)b2*81 + tsp)*64;
      const float* pe = pos_emb + (1+tsp)*64;
      #pragma unroll
      for (int j=0;j<4;j++){
        int col = j*16 + lr;
        dst[col] = fmaxf(acc[i][j][e] + t2c[j], 0.f) + pe[col];
      }
    }
  }
}

// ---------------- LN1 + tsum + SToken squeeze -> xn bf16, tsum f32, sqs f32
__global__ __launch_bounds__(256) void k_ln(const float* __restrict__ stok,
    const float* __restrict__ pos_emb, const float* __restrict__ cls_tok,
    const float* __restrict__ ln1_g, const float* __restrict__ ln1_b,
    const float* __restrict__ Wst, const float* __restrict__ bst,
    const float* __restrict__ bias_st,
    u16* __restrict__ xn, float* __restrict__ tsum, float* __restrict__ sqs){
  __shared__ float pt[2][4][64];
  __shared__ float xs[64];
  __shared__ float sqp[4][64];
  int b = blockIdx.x, tid = threadIdx.x;
  int wv = tid >> 6, d = tid & 63;
  const float* sb = stok + (size_t)b*81*64;
  float lg = ln1_g[d], lb = ln1_b[d];
  float ptok = 0.f, pxn = 0.f;
  for (int t = wv; t < 82; t += 4){
    float xv = (t==0) ? (cls_tok[d] + pos_emb[d]) : sb[(t-1)*64 + d];
    float s1 = xv, s2v = xv*xv;
    #pragma unroll
    for (int off=32; off>0; off>>=1){ s1 += __shfl_xor(s1, off, 64); s2v += __shfl_xor(s2v, off, 64); }
    float mean = s1 * (1.f/64.f);
    float var  = s2v*(1.f/64.f) - mean*mean;
    float xnv = (xv - mean) * rsqrtf(var + 1e-5f) * lg + lb;
    xn[((size_t)b*82 + t)*64 + d] = f2bf(xnv);
    ptok += xv; pxn += xnv;
  }
  pt[0][wv][d] = ptok; pt[1][wv][d] = pxn;
  __syncthreads();
  if (tid < 64){
    tsum[b*64 + d] = pt[0][0][d]+pt[0][1][d]+pt[0][2][d]+pt[0][3][d];
    xs[d] = (pt[1][0][d]+pt[1][1][d]+pt[1][2][d]+pt[1][3][d]) * (1.f/82.f);
  }
  __syncthreads();
  {
    float a = 0.f;
    int k0 = wv*16;
    #pragma unroll
    for (int k=0;k<16;k++) a = fmaf(xs[k0+k], Wst[(k0+k)*64+d], a);
    sqp[wv][d] = a;
  }
  __syncthreads();
  if (tid < 64){
    float a = sqp[0][d]+sqp[1][d]+sqp[2][d]+sqp[3][d] + bst[d];
    a = fmaxf(a, 0.f);
    a = 1.f/(1.f + __expf(-a));
    sqs[b*64 + d] = a + bias_st[d];
  }
}

// ---------------- batched GEMM xn@[Wb|Wc|Wd] (M=335872,N=192,K=64) + fused S6 prep
// B fragments built directly from global f32 weights (no ws residency -> no overlay hazard)
__global__ __launch_bounds__(256, 1) void k_bcd(const u16* __restrict__ xn,
    const float* __restrict__ Wb, const float* __restrict__ Wc, const float* __restrict__ Wd,
    const float* __restrict__ bbv, const float* __restrict__ bcv,
    const float* __restrict__ bdv,
    const float* __restrict__ delta_p, const float* __restrict__ A_p,
    u16* __restrict__ Ax, float* __restrict__ Bxx, u16* __restrict__ Cx){
  __shared__ char At[16384];   // 128 rows x 128B, XOR-swizzled (byte ^ ((row&7)<<4))
  int tid = threadIdx.x;
  int wv = tid >> 6, ln = tid & 63;
  int lq = ln >> 4, lr = ln & 15;
  size_t r0 = (size_t)blockIdx.x * 128;

  // stage A tile (swizzled)
  {
    int row = tid >> 1, hh = tid & 1;
    const char* src = (const char*)xn + (r0 + row)*128 + hh*64;
    #pragma unroll
    for (int c=0;c<4;c++){
      i32x4 v = *(const i32x4*)(src + c*16);
      *(i32x4*)(At + row*128 + ((hh*64 + c*16) ^ ((row&7)<<4))) = v;
    }
  }

  // B fragments from global f32 weights: element (k, c) = W[k*64 + (c&63)]
  bf16x8 bfr[2][12];
  #pragma unroll
  for (int kk=0;kk<2;kk++)
    #pragma unroll
    for (int j=0;j<12;j++){
      int c = j*16 + lr;
      const float* W = (c < 64) ? Wb : ((c < 128) ? Wc : Wd);
      int cc = c & 63;
      int k0 = kk*32 + lq*8;
      bf16x8 f;
      #pragma unroll
      for (int e=0;e<8;e++) f[e] = (short)f2bf(W[(k0+e)*64 + cc]);
      bfr[kk][j] = f;
    }
  __syncthreads();

  f32x4 acc[2][12];
  #pragma unroll
  for (int i=0;i<2;i++)
    #pragma unroll
    for (int j=0;j<12;j++) acc[i][j] = (f32x4){0.f,0.f,0.f,0.f};

  #pragma unroll
  for (int kk=0;kk<2;kk++){
    bf16x8 afr[2];
    #pragma unroll
    for (int i=0;i<2;i++){
      int row = wv*32 + i*16 + lr;
      afr[i] = *(const bf16x8*)(At + row*128 + ((kk*64 + lq*16) ^ ((row&7)<<4)));
    }
    #pragma unroll
    for (int i=0;i<2;i++)
      #pragma unroll
      for (int j=0;j<12;j++)
        acc[i][j] = __builtin_amdgcn_mfma_f32_16x16x32_bf16(afr[i], bfr[kk][j], acc[i][j], 0, 0, 0);
  }

  // epilogue: lane holds (B0, C, Draw) for dim d = j*16+lr at j, j+4, j+8
  #pragma unroll
  for (int i=0;i<2;i++){
    #pragma unroll
    for (int e=0;e<4;e++){
      int row = wv*32 + i*16 + lq*4 + e;
      unsigned rr = (unsigned)(r0 + row);
      unsigned t = rr % 82u;
      #pragma unroll
      for (int j=0;j<4;j++){
        int d = j*16 + lr;
        float B0 = acc[i][j][e]   + bbv[d];
        float Cv = acc[i][j+4][e] + bcv[d];
        float Dr = acc[i][j+8][e] + bdv[d] + delta_p[t*64+d];
        float D  = 1.f/(1.f + __expf(-Dr));
        int byte = j*32 + lr*2;
        float xv = bf2f(*(const u16*)(At + row*128 + (byte ^ ((row&7)<<4))));
        size_t o = (size_t)rr*64 + d;
        Ax[o]  = f2bf(D * A_p[t*64+d]);
        Bxx[o] = D * B0 * xv;
        Cx[o]  = f2bf(Cv);
      }
    }
  }
}

// ---------------- scan + pool + LN2 + MLP (wave per batch, lane per dim)
__global__ __launch_bounds__(256) void k_scan(const u16* __restrict__ xn,
    const u16* __restrict__ Ax, const float* __restrict__ Bxx, const u16* __restrict__ Cx,
    const float* __restrict__ tsum, const float* __restrict__ sqs,
    const float* __restrict__ ln2_g, const float* __restrict__ ln2_b,
    const float* __restrict__ Wm1, const float* __restrict__ bm1,
    const float* __restrict__ Wm2, const float* __restrict__ bm2,
    float* __restrict__ out){
  int tid = threadIdx.x, wv = tid >> 6, d = tid & 63;
  int b = blockIdx.x*4 + wv;
  float sq = sqs[b*64 + d];
  float s = 0.f, racc = 0.f;
  size_t base = (size_t)b*82*64 + d;
  #pragma unroll 2
  for (int t = 0; t < 82; t++){
    float a  = bf2f(Ax[base]);
    float bx = Bxx[base];
    float c  = bf2f(Cx[base]);
    float xv = bf2f(xn[base]);
    s = fmaf(a, s, bx);
    float o = fmaf(c, s, sq*xv);
    float z = 1.f/(1.f + __expf(-xv));
    racc = fmaf(o, z, racc);
    base += 64;
  }
  float pooled = (tsum[b*64 + d] + racc) * (1.f/82.f);
  float s1 = pooled, s2v = pooled*pooled;
  #pragma unroll
  for (int off=32; off>0; off>>=1){ s1 += __shfl_xor(s1, off, 64); s2v += __shfl_xor(s2v, off, 64); }
  float mean = s1*(1.f/64.f), var = s2v*(1.f/64.f) - mean*mean;
  float yn = (pooled - mean)*rsqrtf(var + 1e-5f)*ln2_g[d] + ln2_b[d];
  float a1 = bm1[d];
  for (int k=0;k<64;k++) a1 = fmaf(__shfl(yn, k, 64), Wm1[k*64+d], a1);
  float hg = 0.5f*a1*(1.f + erff(a1*0.70710678118654752f));
  float a2 = bm2[d];
  for (int k=0;k<64;k++) a2 = fmaf(__shfl(hg, k, 64), Wm2[k*64+d], a2);
  out[b*64 + d] = pooled + a2;
}

extern "C" void kernel_launch(void* const* d_in, const int* in_sizes, int n_in,
                              void* d_out, int out_size, void* d_ws, size_t ws_size,
                              hipStream_t stream){
  const float* x       = (const float*)d_in[0];
  const float* w3      = (const float*)d_in[1];
  const float* b3      = (const float*)d_in[2];
  const float* g3      = (const float*)d_in[3];
  const float* be3     = (const float*)d_in[4];
  const float* m3      = (const float*)d_in[5];
  const float* v3      = (const float*)d_in[6];
  const float* w2c     = (const float*)d_in[7];
  const float* b2c     = (const float*)d_in[8];
  const float* g2      = (const float*)d_in[9];
  const float* be2     = (const float*)d_in[10];
  const float* m2      = (const float*)d_in[11];
  const float* v2      = (const float*)d_in[12];
  const float* pos_emb = (const float*)d_in[13];
  const float* cls_tok = (const float*)d_in[14];
  const float* ln1_g   = (const float*)d_in[15];
  const float* ln1_b   = (const float*)d_in[16];
  const float* Wb      = (const float*)d_in[17];
  const float* bbv     = (const float*)d_in[18];
  const float* Wc      = (const float*)d_in[19];
  const float* bc      = (const float*)d_in[20];
  const float* Wd      = (const float*)d_in[21];
  const float* bd      = (const float*)d_in[22];
  const float* delta_p = (const float*)d_in[23];
  const float* A_p     = (const float*)d_in[24];
  const float* Wst     = (const float*)d_in[25];
  const float* bst     = (const float*)d_in[26];
  const float* bias_st = (const float*)d_in[27];
  const float* ln2_g   = (const float*)d_in[28];
  const float* ln2_b   = (const float*)d_in[29];
  const float* Wm1     = (const float*)d_in[30];
  const float* bm1     = (const float*)d_in[31];
  const float* Wm2     = (const float*)d_in[32];
  const float* bm2     = (const float*)d_in[33];

  // workspace layout (bytes), peak = 244,506,624 (same as passing round-1):
  //   phase A: h1 [0,159252480) | Wt2 [159252480,159547392) | stok [159571968,244506624)
  //   phase B overlays (each region's writer strictly precedes all its readers):
  //     xn   [0,         42991616)  over dead h1     (k_ln W -> k_bcd/k_scan R)
  //     Ax   [42991616,  85983232)  over dead h1     (k_bcd W -> k_scan R)
  //     Cx   [85983232, 128974848)  over dead h1     (k_bcd W -> k_scan R)
  //     tsum [128974848,130023424)  over dead h1     (k_ln W -> k_scan R)
  //     sqs  [130023424,131072000)  over dead h1     (k_ln W -> k_scan R)
  //     Bxx  [131072000,217055232)  over dead h1-tail + dead Wt2 + dead stok-head
  //                                  (k_bcd W -> k_scan R; stok dead after k_ln)
  char* ws = (char*)d_ws;
  u16*   h1   = (u16*)ws;
  u16*   Wt2  = (u16*)(ws + 159252480);
  float* stok = (float*)(ws + 159571968);
  u16*   xnb  = (u16*)ws;
  u16*   Ax   = (u16*)(ws + 42991616);
  u16*   Cx   = (u16*)(ws + 85983232);
  float* tsum = (float*)(ws + 128974848);
  float* sqs  = (float*)(ws + 130023424);
  float* Bxx  = (float*)(ws + 131072000);

  k_wt    <<<576,  256, 0, stream>>>(w2c, g2, v2, Wt2);
  k_conv3d<<<4096, 256, 0, stream>>>(x, w3, b3, g3, be3, m3, v3, h1);
  k_conv2d<<<2592, 256, 0, stream>>>(h1, Wt2, b2c, g2, be2, m2, v2, pos_emb, stok);
  k_ln    <<<4096, 256, 0, stream>>>(stok, pos_emb, cls_tok, ln1_g, ln1_b,
                                     Wst, bst, bias_st, xnb, tsum, sqs);
  k_bcd   <<<2624, 256, 0, stream>>>(xnb, Wb, Wc, Wd, bbv, bc, bd, delta_p, A_p,
                                     Ax, Bxx, Cx);
  k_scan  <<<1024, 256, 0, stream>>>(xnb, Ax, Bxx, Cx, tsum, sqs,
                                     ln2_g, ln2_b, Wm1, bm1, Wm2, bm2, (float*)d_out);
}

// Round 4
// 537.733 us; speedup vs baseline: 2.1043x; 1.2350x over previous
//
#include <hip/hip_runtime.h>

typedef unsigned short u16;
typedef __attribute__((ext_vector_type(8))) short bf16x8;
typedef __attribute__((ext_vector_type(4))) float f32x4;
typedef __attribute__((ext_vector_type(4))) int i32x4;

#define DEV __device__ __forceinline__

DEV u16 f2bf(float f){
  unsigned u = __float_as_uint(f);
  u += 0x7fffu + ((u >> 16) & 1u);
  return (u16)(u >> 16);
}
DEV float bf2f(u16 h){ return __uint_as_float(((unsigned)h) << 16); }

// Inverse spiral map: pixel index (0..80) -> spiral token position (0..80).
DEV int spiral_t(int pix){
  int px = pix / 9, py = pix % 9;
  int dr = px - 4, dc = py - 4;
  int ar = dr < 0 ? -dr : dr, ac = dc < 0 ? -dc : dc;
  int r = ar > ac ? ar : ac;
  if (r == 0) return 0;
  int start = 1 + 4*r*(r-1);
  if (dr == -r && dc >= -r+1) return start + dc + r - 1;
  if (dc == r)  return start + 2*r + dr + r - 1;
  if (dr == r)  return start + 4*r + dc + r;
  return start + 6*r + dr + r;
}

// ---------------- weight prep: Wt2 (conv2d tiles, BN folded)
__global__ __launch_bounds__(256) void k_wt(const float* __restrict__ w2c,
                                            const float* __restrict__ g2,
                                            const float* __restrict__ v2,
                                            u16* __restrict__ Wt2){
  int idx = blockIdx.x*256 + threadIdx.x;
  if (idx >= 72*64*32) return;
  int kk = idx & 31;
  int o  = (idx >> 5) & 63;
  int tile = idx >> 11;          // 0..71
  int dxy = tile >> 3;           // 0..8
  int chunk = tile & 7;          // 0..7
  int ch = chunk*32 + kk;        // padded channel
  float v = 0.f;
  if (ch < 240){
    float s2 = g2[o] * rsqrtf(v2[o] + 1e-5f);
    v = w2c[(o*240 + ch)*9 + dxy] * s2;
  }
  Wt2[idx] = f2bf(v);
}

// ---------------- conv3d (1->8, k=3^3, SAME) + BN + ReLU -> h1 bf16 [B][81][240]
// v2: zero-padded LDS tile [32][11][11]; thread owns (pix,dd), loads 27 vals to
// registers once, computes all 8 co outputs (8x fewer LDS reads than v1).
__global__ __launch_bounds__(256) void k_conv3d(const float* __restrict__ x,
    const float* __restrict__ w3, const float* __restrict__ b3,
    const float* __restrict__ g3, const float* __restrict__ be3,
    const float* __restrict__ m3, const float* __restrict__ v3,
    u16* __restrict__ h1){
  __shared__ float tile[3872];   // [dd+1][px+1][py+1] : 32*11*11, zero-padded borders
  __shared__ float wle[216];
  __shared__ float sc[8], sh[8];
  int b = blockIdx.x, tid = threadIdx.x;
  for (int i = tid; i < 3872; i += 256) tile[i] = 0.f;
  if (tid < 216) wle[tid] = w3[tid];
  if (tid < 8){
    float s = g3[tid]*rsqrtf(v3[tid]+1e-5f);
    sc[tid] = s;
    sh[tid] = (b3[tid]-m3[tid])*s + be3[tid];
  }
  __syncthreads();
  const float* xin = x + b*2430;
  for (int i = tid; i < 2430; i += 256){
    int dd = i / 81, rem = i % 81;
    int px = rem / 9, py = rem % 9;
    tile[(dd+1)*121 + (px+1)*11 + (py+1)] = xin[i];
  }
  __syncthreads();
  u16* hb = h1 + (size_t)b*19440;
  for (int p = tid; p < 2430; p += 256){
    int pix = p / 30, dd = p % 30;          // dd fastest across lanes -> coalesced-ish stores
    int px = pix / 9, py = pix % 9;
    const float* tp = tile + dd*121 + px*11 + py;   // padded corner of 3x3x3 window
    float v[27];
    #pragma unroll
    for (int kd=0;kd<3;kd++)
      #pragma unroll
      for (int kx=0;kx<3;kx++)
        #pragma unroll
        for (int ky=0;ky<3;ky++)
          v[(kd*3+kx)*3+ky] = tp[kd*121 + kx*11 + ky];
    u16* hp = hb + pix*240 + dd;            // ch = co*30 + dd
    #pragma unroll
    for (int co=0;co<8;co++){
      float acc = 0.f;
      const float* wp = wle + co*27;
      #pragma unroll
      for (int q=0;q<27;q++) acc = fmaf(v[q], wp[q], acc);
      hp[co*30] = f2bf(fmaxf(acc*sc[co] + sh[co], 0.f));
    }
  }
}

// ---------------- conv2d as MFMA GEMM + BN + ReLU + spiral scatter + pos_emb
// v2: KB=64 (72->36 iters, half the barriers), padded LDS rows (144B stride,
// 2-way bank aliasing = free), register prefetch of next iter's global loads.
__global__ __launch_bounds__(256) void k_conv2d(const u16* __restrict__ h1,
    const u16* __restrict__ Wt2,
    const float* __restrict__ b2c, const float* __restrict__ g2,
    const float* __restrict__ be2, const float* __restrict__ m2,
    const float* __restrict__ v2,
    const float* __restrict__ pos_emb, float* __restrict__ stok){
  __shared__ char Al[128*144];   // 128 rows x 64 k (128B) + 16B pad
  __shared__ char Bl[64*144];    //  64 cols x 64 k (128B) + 16B pad
  int tid = threadIdx.x;
  int bm = blockIdx.x;

  // A staging ids: 2 threads per row, 64B each
  int r = tid >> 1, hh = tid & 1;
  int gm = bm*128 + r;
  unsigned bA = (unsigned)gm / 81u;
  unsigned pixA = (unsigned)gm % 81u;
  int px = (int)pixA / 9, py = (int)pixA % 9;
  const u16* h1b = h1 + (size_t)bA*19440;
  // B staging ids: 4 threads per col-row, 32B each
  int bo = tid >> 2, bq = tid & 3;

  int wv = tid >> 6, ln = tid & 63;
  int lq = ln >> 4, lr = ln & 15;

  f32x4 acc[2][4];
  #pragma unroll
  for (int i=0;i<2;i++)
    #pragma unroll
    for (int j=0;j<4;j++) acc[i][j] = (f32x4){0.f,0.f,0.f,0.f};

  i32x4 aR[4], bR[2];
  auto LOADI = [&](int it){
    int dxy = it >> 2, c0 = (it & 3) << 6;          // K = dxy*256 + c, c0 in {0,64,128,192}
    int dx = dxy/3 - 1, dy = dxy%3 - 1;
    int px2 = px + dx, py2 = py + dy;
    bool pv = (px2>=0 && px2<9 && py2>=0 && py2<9);
    const u16* arow = h1b + (px2*9+py2)*240 + c0 + hh*32;
    int cb = c0 + hh*32;
    #pragma unroll
    for (int e=0;e<4;e++){
      bool ok = pv && (cb + e*8 < 240);
      aR[e] = ok ? *(const i32x4*)(arow + e*8) : (i32x4){0,0,0,0};
    }
    #pragma unroll
    for (int p=0;p<2;p++){
      int k0p = bq*16 + p*8;                         // k local in [0,64)
      const u16* src = Wt2 + (size_t)(dxy*8 + (c0>>5) + (k0p>>5))*2048 + bo*32 + (k0p & 31);
      bR[p] = *(const i32x4*)src;
    }
  };

  LOADI(0);
  for (int it = 0; it < 36; it++){
    __syncthreads();                 // prev iter's readers done
    {
      char* ad = Al + r*144 + hh*64;
      *(i32x4*)(ad   ) = aR[0];
      *(i32x4*)(ad+16) = aR[1];
      *(i32x4*)(ad+32) = aR[2];
      *(i32x4*)(ad+48) = aR[3];
      char* bd = Bl + bo*144 + bq*32;
      *(i32x4*)(bd   ) = bR[0];
      *(i32x4*)(bd+16) = bR[1];
    }
    __syncthreads();
    if (it + 1 < 36) LOADI(it + 1);  // issue next loads; consumed after next barrier
    bf16x8 afr[2][2], bfr[4][2];
    #pragma unroll
    for (int kk=0;kk<2;kk++){
      #pragma unroll
      for (int i=0;i<2;i++){
        int row = (wv*2+i)*16 + lr;
        afr[i][kk] = *(const bf16x8*)(Al + row*144 + kk*64 + lq*16);
      }
      #pragma unroll
      for (int j=0;j<4;j++){
        bfr[j][kk] = *(const bf16x8*)(Bl + (j*16+lr)*144 + kk*64 + lq*16);
      }
    }
    #pragma unroll
    for (int kk=0;kk<2;kk++)
      #pragma unroll
      for (int i=0;i<2;i++)
        #pragma unroll
        for (int j=0;j<4;j++)
          acc[i][j] = __builtin_amdgcn_mfma_f32_16x16x32_bf16(afr[i][kk], bfr[j][kk], acc[i][j], 0, 0, 0);
  }

  float t2c[4];
  #pragma unroll
  for (int j=0;j<4;j++){
    int col = j*16 + lr;
    float s2 = g2[col]*rsqrtf(v2[col]+1e-5f);
    t2c[j] = (b2c[col]-m2[col])*s2 + be2[col];
  }
  #pragma unroll
  for (int i=0;i<2;i++){
    #pragma unroll
    for (int e=0;e<4;e++){
      int row = (wv*2+i)*16 + lq*4 + e;
      int gm2 = bm*128 + row;
      unsigned b2 = (unsigned)gm2 / 81u;
      unsigned pix2 = (unsigned)gm2 % 81u;
      int tsp = spiral_t((int)pix2);
      float* dst = stok + ((size_t)b2*81 + tsp)*64;
      const float* pe = pos_emb + (1+tsp)*64;
      #pragma unroll
      for (int j=0;j<4;j++){
        int col = j*16 + lr;
        dst[col] = fmaxf(acc[i][j][e] + t2c[j], 0.f) + pe[col];
      }
    }
  }
}

// ---------------- LN1 + tsum + SToken squeeze -> xn bf16, tsum f32, sqs f32
__global__ __launch_bounds__(256) void k_ln(const float* __restrict__ stok,
    const float* __restrict__ pos_emb, const float* __restrict__ cls_tok,
    const float* __restrict__ ln1_g, const float* __restrict__ ln1_b,
    const float* __restrict__ Wst, const float* __restrict__ bst,
    const float* __restrict__ bias_st,
    u16* __restrict__ xn, float* __restrict__ tsum, float* __restrict__ sqs){
  __shared__ float pt[2][4][64];
  __shared__ float xs[64];
  __shared__ float sqp[4][64];
  int b = blockIdx.x, tid = threadIdx.x;
  int wv = tid >> 6, d = tid & 63;
  const float* sb = stok + (size_t)b*81*64;
  float lg = ln1_g[d], lb = ln1_b[d];
  float ptok = 0.f, pxn = 0.f;
  for (int t = wv; t < 82; t += 4){
    float xv = (t==0) ? (cls_tok[d] + pos_emb[d]) : sb[(t-1)*64 + d];
    float s1 = xv, s2v = xv*xv;
    #pragma unroll
    for (int off=32; off>0; off>>=1){ s1 += __shfl_xor(s1, off, 64); s2v += __shfl_xor(s2v, off, 64); }
    float mean = s1 * (1.f/64.f);
    float var  = s2v*(1.f/64.f) - mean*mean;
    float xnv = (xv - mean) * rsqrtf(var + 1e-5f) * lg + lb;
    xn[((size_t)b*82 + t)*64 + d] = f2bf(xnv);
    ptok += xv; pxn += xnv;
  }
  pt[0][wv][d] = ptok; pt[1][wv][d] = pxn;
  __syncthreads();
  if (tid < 64){
    tsum[b*64 + d] = pt[0][0][d]+pt[0][1][d]+pt[0][2][d]+pt[0][3][d];
    xs[d] = (pt[1][0][d]+pt[1][1][d]+pt[1][2][d]+pt[1][3][d]) * (1.f/82.f);
  }
  __syncthreads();
  {
    float a = 0.f;
    int k0 = wv*16;
    #pragma unroll
    for (int k=0;k<16;k++) a = fmaf(xs[k0+k], Wst[(k0+k)*64+d], a);
    sqp[wv][d] = a;
  }
  __syncthreads();
  if (tid < 64){
    float a = sqp[0][d]+sqp[1][d]+sqp[2][d]+sqp[3][d] + bst[d];
    a = fmaxf(a, 0.f);
    a = 1.f/(1.f + __expf(-a));
    sqs[b*64 + d] = a + bias_st[d];
  }
}

// ---------------- batched GEMM xn@[Wb|Wc|Wd] (M=335872,N=192,K=64) + fused S6 prep
__global__ __launch_bounds__(256, 1) void k_bcd(const u16* __restrict__ xn,
    const float* __restrict__ Wb, const float* __restrict__ Wc, const float* __restrict__ Wd,
    const float* __restrict__ bbv, const float* __restrict__ bcv,
    const float* __restrict__ bdv,
    const float* __restrict__ delta_p, const float* __restrict__ A_p,
    u16* __restrict__ Ax, float* __restrict__ Bxx, u16* __restrict__ Cx){
  __shared__ char At[16384];   // 128 rows x 128B, XOR-swizzled (byte ^ ((row&7)<<4))
  int tid = threadIdx.x;
  int wv = tid >> 6, ln = tid & 63;
  int lq = ln >> 4, lr = ln & 15;
  size_t r0 = (size_t)blockIdx.x * 128;

  // stage A tile (swizzled)
  {
    int row = tid >> 1, hh = tid & 1;
    const char* src = (const char*)xn + (r0 + row)*128 + hh*64;
    #pragma unroll
    for (int c=0;c<4;c++){
      i32x4 v = *(const i32x4*)(src + c*16);
      *(i32x4*)(At + row*128 + ((hh*64 + c*16) ^ ((row&7)<<4))) = v;
    }
  }

  // B fragments from global f32 weights: element (k, c) = W[k*64 + (c&63)]
  bf16x8 bfr[2][12];
  #pragma unroll
  for (int kk=0;kk<2;kk++)
    #pragma unroll
    for (int j=0;j<12;j++){
      int c = j*16 + lr;
      const float* W = (c < 64) ? Wb : ((c < 128) ? Wc : Wd);
      int cc = c & 63;
      int k0 = kk*32 + lq*8;
      bf16x8 f;
      #pragma unroll
      for (int e=0;e<8;e++) f[e] = (short)f2bf(W[(k0+e)*64 + cc]);
      bfr[kk][j] = f;
    }
  __syncthreads();

  f32x4 acc[2][12];
  #pragma unroll
  for (int i=0;i<2;i++)
    #pragma unroll
    for (int j=0;j<12;j++) acc[i][j] = (f32x4){0.f,0.f,0.f,0.f};

  #pragma unroll
  for (int kk=0;kk<2;kk++){
    bf16x8 afr[2];
    #pragma unroll
    for (int i=0;i<2;i++){
      int row = wv*32 + i*16 + lr;
      afr[i] = *(const bf16x8*)(At + row*128 + ((kk*64 + lq*16) ^ ((row&7)<<4)));
    }
    #pragma unroll
    for (int i=0;i<2;i++)
      #pragma unroll
      for (int j=0;j<12;j++)
        acc[i][j] = __builtin_amdgcn_mfma_f32_16x16x32_bf16(afr[i], bfr[kk][j], acc[i][j], 0, 0, 0);
  }

  // epilogue: lane holds (B0, C, Draw) for dim d = j*16+lr at j, j+4, j+8
  #pragma unroll
  for (int i=0;i<2;i++){
    #pragma unroll
    for (int e=0;e<4;e++){
      int row = wv*32 + i*16 + lq*4 + e;
      unsigned rr = (unsigned)(r0 + row);
      unsigned t = rr % 82u;
      #pragma unroll
      for (int j=0;j<4;j++){
        int d = j*16 + lr;
        float B0 = acc[i][j][e]   + bbv[d];
        float Cv = acc[i][j+4][e] + bcv[d];
        float Dr = acc[i][j+8][e] + bdv[d] + delta_p[t*64+d];
        float D  = 1.f/(1.f + __expf(-Dr));
        int byte = j*32 + lr*2;
        float xv = bf2f(*(const u16*)(At + row*128 + (byte ^ ((row&7)<<4))));
        size_t o = (size_t)rr*64 + d;
        Ax[o]  = f2bf(D * A_p[t*64+d]);
        Bxx[o] = D * B0 * xv;
        Cx[o]  = f2bf(Cv);
      }
    }
  }
}

// ---------------- scan + pool + LN2 + MLP (wave per batch, lane per dim)
__global__ __launch_bounds__(256) void k_scan(const u16* __restrict__ xn,
    const u16* __restrict__ Ax, const float* __restrict__ Bxx, const u16* __restrict__ Cx,
    const float* __restrict__ tsum, const float* __restrict__ sqs,
    const float* __restrict__ ln2_g, const float* __restrict__ ln2_b,
    const float* __restrict__ Wm1, const float* __restrict__ bm1,
    const float* __restrict__ Wm2, const float* __restrict__ bm2,
    float* __restrict__ out){
  int tid = threadIdx.x, wv = tid >> 6, d = tid & 63;
  int b = blockIdx.x*4 + wv;
  float sq = sqs[b*64 + d];
  float s = 0.f, racc = 0.f;
  size_t base = (size_t)b*82*64 + d;
  #pragma unroll 2
  for (int t = 0; t < 82; t++){
    float a  = bf2f(Ax[base]);
    float bx = Bxx[base];
    float c  = bf2f(Cx[base]);
    float xv = bf2f(xn[base]);
    s = fmaf(a, s, bx);
    float o = fmaf(c, s, sq*xv);
    float z = 1.f/(1.f + __expf(-xv));
    racc = fmaf(o, z, racc);
    base += 64;
  }
  float pooled = (tsum[b*64 + d] + racc) * (1.f/82.f);
  float s1 = pooled, s2v = pooled*pooled;
  #pragma unroll
  for (int off=32; off>0; off>>=1){ s1 += __shfl_xor(s1, off, 64); s2v += __shfl_xor(s2v, off, 64); }
  float mean = s1*(1.f/64.f), var = s2v*(1.f/64.f) - mean*mean;
  float yn = (pooled - mean)*rsqrtf(var + 1e-5f)*ln2_g[d] + ln2_b[d];
  float a1 = bm1[d];
  for (int k=0;k<64;k++) a1 = fmaf(__shfl(yn, k, 64), Wm1[k*64+d], a1);
  float hg = 0.5f*a1*(1.f + erff(a1*0.70710678118654752f));
  float a2 = bm2[d];
  for (int k=0;k<64;k++) a2 = fmaf(__shfl(hg, k, 64), Wm2[k*64+d], a2);
  out[b*64 + d] = pooled + a2;
}

extern "C" void kernel_launch(void* const* d_in, const int* in_sizes, int n_in,
                              void* d_out, int out_size, void* d_ws, size_t ws_size,
                              hipStream_t stream){
  const float* x       = (const float*)d_in[0];
  const float* w3      = (const float*)d_in[1];
  const float* b3      = (const float*)d_in[2];
  const float* g3      = (const float*)d_in[3];
  const float* be3     = (const float*)d_in[4];
  const float* m3      = (const float*)d_in[5];
  const float* v3      = (const float*)d_in[6];
  const float* w2c     = (const float*)d_in[7];
  const float* b2c     = (const float*)d_in[8];
  const float* g2      = (const float*)d_in[9];
  const float* be2     = (const float*)d_in[10];
  const float* m2      = (const float*)d_in[11];
  const float* v2      = (const float*)d_in[12];
  const float* pos_emb = (const float*)d_in[13];
  const float* cls_tok = (const float*)d_in[14];
  const float* ln1_g   = (const float*)d_in[15];
  const float* ln1_b   = (const float*)d_in[16];
  const float* Wb      = (const float*)d_in[17];
  const float* bbv     = (const float*)d_in[18];
  const float* Wc      = (const float*)d_in[19];
  const float* bc      = (const float*)d_in[20];
  const float* Wd      = (const float*)d_in[21];
  const float* bd      = (const float*)d_in[22];
  const float* delta_p = (const float*)d_in[23];
  const float* A_p     = (const float*)d_in[24];
  const float* Wst     = (const float*)d_in[25];
  const float* bst     = (const float*)d_in[26];
  const float* bias_st = (const float*)d_in[27];
  const float* ln2_g   = (const float*)d_in[28];
  const float* ln2_b   = (const float*)d_in[29];
  const float* Wm1     = (const float*)d_in[30];
  const float* bm1     = (const float*)d_in[31];
  const float* Wm2     = (const float*)d_in[32];
  const float* bm2     = (const float*)d_in[33];

  // workspace layout (bytes), peak = 244,506,624:
  //   phase A: h1 [0,159252480) | Wt2 [159252480,159547392) | stok [159571968,244506624)
  //   phase B overlays (writer strictly precedes all readers):
  //     xn   [0,         42991616)  | Ax [42991616,85983232) | Cx [85983232,128974848)
  //     tsum [128974848,130023424)  | sqs [130023424,131072000)
  //     Bxx  [131072000,217055232)  over dead h1-tail + dead Wt2 + dead stok-head
  char* ws = (char*)d_ws;
  u16*   h1   = (u16*)ws;
  u16*   Wt2  = (u16*)(ws + 159252480);
  float* stok = (float*)(ws + 159571968);
  u16*   xnb  = (u16*)ws;
  u16*   Ax   = (u16*)(ws + 42991616);
  u16*   Cx   = (u16*)(ws + 85983232);
  float* tsum = (float*)(ws + 128974848);
  float* sqs  = (float*)(ws + 130023424);
  float* Bxx  = (float*)(ws + 131072000);

  k_wt    <<<576,  256, 0, stream>>>(w2c, g2, v2, Wt2);
  k_conv3d<<<4096, 256, 0, stream>>>(x, w3, b3, g3, be3, m3, v3, h1);
  k_conv2d<<<2592, 256, 0, stream>>>(h1, Wt2, b2c, g2, be2, m2, v2, pos_emb, stok);
  k_ln    <<<4096, 256, 0, stream>>>(stok, pos_emb, cls_tok, ln1_g, ln1_b,
                                     Wst, bst, bias_st, xnb, tsum, sqs);
  k_bcd   <<<2624, 256, 0, stream>>>(xnb, Wb, Wc, Wd, bbv, bc, bd, delta_p, A_p,
                                     Ax, Bxx, Cx);
  k_scan  <<<1024, 256, 0, stream>>>(xnb, Ax, Bxx, Cx, tsum, sqs,
                                     ln2_g, ln2_b, Wm1, bm1, Wm2, bm2, (float*)d_out);
}

// Round 5
// 498.472 us; speedup vs baseline: 2.2700x; 1.0788x over previous
//
#include <hip/hip_runtime.h>

typedef unsigned short u16;
typedef __attribute__((ext_vector_type(8))) short bf16x8;
typedef __attribute__((ext_vector_type(4))) float f32x4;
typedef __attribute__((ext_vector_type(4))) int i32x4;

#define DEV __device__ __forceinline__

DEV u16 f2bf(float f){
  unsigned u = __float_as_uint(f);
  u += 0x7fffu + ((u >> 16) & 1u);
  return (u16)(u >> 16);
}
DEV float bf2f(u16 h){ return __uint_as_float(((unsigned)h) << 16); }

// Inverse spiral map: pixel index (0..80) -> spiral token position (0..80).
DEV int spiral_t(int pix){
  int px = pix / 9, py = pix % 9;
  int dr = px - 4, dc = py - 4;
  int ar = dr < 0 ? -dr : dr, ac = dc < 0 ? -dc : dc;
  int r = ar > ac ? ar : ac;
  if (r == 0) return 0;
  int start = 1 + 4*r*(r-1);
  if (dr == -r && dc >= -r+1) return start + dc + r - 1;
  if (dc == r)  return start + 2*r + dr + r - 1;
  if (dr == r)  return start + 4*r + dc + r;
  return start + 6*r + dr + r;
}

// ---------------- weight prep: Wt2 (conv2d tiles, BN folded)
__global__ __launch_bounds__(256) void k_wt(const float* __restrict__ w2c,
                                            const float* __restrict__ g2,
                                            const float* __restrict__ v2,
                                            u16* __restrict__ Wt2){
  int idx = blockIdx.x*256 + threadIdx.x;
  if (idx >= 72*64*32) return;
  int kk = idx & 31;
  int o  = (idx >> 5) & 63;
  int tile = idx >> 11;          // 0..71
  int dxy = tile >> 3;           // 0..8
  int chunk = tile & 7;          // 0..7
  int ch = chunk*32 + kk;        // padded channel
  float v = 0.f;
  if (ch < 240){
    float s2 = g2[o] * rsqrtf(v2[o] + 1e-5f);
    v = w2c[(o*240 + ch)*9 + dxy] * s2;
  }
  Wt2[idx] = f2bf(v);
}

// ---------------- conv3d (1->8, k=3^3, SAME) + BN + ReLU -> h1 bf16 [B][81][240]
__global__ __launch_bounds__(256) void k_conv3d(const float* __restrict__ x,
    const float* __restrict__ w3, const float* __restrict__ b3,
    const float* __restrict__ g3, const float* __restrict__ be3,
    const float* __restrict__ m3, const float* __restrict__ v3,
    u16* __restrict__ h1){
  __shared__ float tile[3872];   // [dd+1][px+1][py+1] : 32*11*11, zero-padded borders
  __shared__ float wle[216];
  __shared__ float sc[8], sh[8];
  int b = blockIdx.x, tid = threadIdx.x;
  for (int i = tid; i < 3872; i += 256) tile[i] = 0.f;
  if (tid < 216) wle[tid] = w3[tid];
  if (tid < 8){
    float s = g3[tid]*rsqrtf(v3[tid]+1e-5f);
    sc[tid] = s;
    sh[tid] = (b3[tid]-m3[tid])*s + be3[tid];
  }
  __syncthreads();
  const float* xin = x + b*2430;
  for (int i = tid; i < 2430; i += 256){
    int dd = i / 81, rem = i % 81;
    int px = rem / 9, py = rem % 9;
    tile[(dd+1)*121 + (px+1)*11 + (py+1)] = xin[i];
  }
  __syncthreads();
  u16* hb = h1 + (size_t)b*19440;
  for (int p = tid; p < 2430; p += 256){
    int pix = p / 30, dd = p % 30;
    int px = pix / 9, py = pix % 9;
    const float* tp = tile + dd*121 + px*11 + py;
    float v[27];
    #pragma unroll
    for (int kd=0;kd<3;kd++)
      #pragma unroll
      for (int kx=0;kx<3;kx++)
        #pragma unroll
        for (int ky=0;ky<3;ky++)
          v[(kd*3+kx)*3+ky] = tp[kd*121 + kx*11 + ky];
    u16* hp = hb + pix*240 + dd;
    #pragma unroll
    for (int co=0;co<8;co++){
      float acc = 0.f;
      const float* wp = wle + co*27;
      #pragma unroll
      for (int q=0;q<27;q++) acc = fmaf(v[q], wp[q], acc);
      hp[co*30] = f2bf(fmaxf(acc*sc[co] + sh[co], 0.f));
    }
  }
}

// ---------------- conv2d as image-resident-LDS MFMA GEMM + BN + ReLU + spiral scatter + pos_emb
// v3: block owns 3 images staged ONCE into LDS (row stride 528B = 132 words -> balanced
// banks on b128); im2col A-frags read from LDS per tap; per-tap B slab (raw Wt2 layout)
// prefetched one tap ahead; invalid reads -> zeroed LDS row (broadcast).
__global__ __launch_bounds__(256, 1) void k_conv2d(const u16* __restrict__ h1,
    const u16* __restrict__ Wt2,
    const float* __restrict__ b2c, const float* __restrict__ g2,
    const float* __restrict__ be2, const float* __restrict__ m2,
    const float* __restrict__ v2,
    const float* __restrict__ pos_emb, float* __restrict__ stok){
  // layout: rows r in [0,243): image data at r*528 (480B data + 32B zero-ch + 16B pad)
  //         zrow at 128304 (528B zeros); BL at 128832: [8 cc][64 o][32 k] u16 = 32768B
  __shared__ __align__(16) char smem[161600];
  const int ZROW = 128304, BLo = 128832;
  int tid = threadIdx.x;
  int wv = tid >> 6, ln = tid & 63;
  int lq = ln >> 4, lr = ln & 15;
  int img0 = blockIdx.x*3;
  long grow0 = (long)img0*81;

  // B prefetch (tap 0) into registers while we stage images
  i32x4 pf[8];
  #pragma unroll
  for (int u=0;u<8;u++)
    pf[u] = *(const i32x4*)(Wt2 + (u*256+tid)*8);

  // zero fills: per-row channel-pad words [120,128) + zrow
  for (int idx = tid; idx < 243*8; idx += 256){
    int r = idx >> 3, w = idx & 7;
    *(float*)(smem + r*528 + 480 + w*4) = 0.f;
  }
  if (tid < 132) *(float*)(smem + ZROW + tid*4) = 0.f;
  // stage 3 images: 243 rows x 30 chunks of 16B, coalesced
  for (int idx = tid; idx < 243*30; idx += 256){
    int r = idx / 30, c = idx % 30;
    if (grow0 + r < 331776)
      *(i32x4*)(smem + r*528 + c*16) =
        *(const i32x4*)(h1 + (grow0 + r)*240 + c*8);
  }
  __syncthreads();

  f32x4 acc[4][4];
  #pragma unroll
  for (int i=0;i<4;i++)
    #pragma unroll
    for (int j=0;j<4;j++) acc[i][j] = (f32x4){0.f,0.f,0.f,0.f};

  // tap-invariant lane base for B reads
  int bB = BLo + (ln & 15)*64 + lq*16;   // + j*1024 + cc*4096 later

  for (int tap = 0; tap < 9; tap++){
    // write prefetched B slab to LDS
    #pragma unroll
    for (int u=0;u<8;u++)
      *(i32x4*)(smem + BLo + (u*256+tid)*16) = pf[u];
    if (tap < 8){
      #pragma unroll
      for (int u=0;u<8;u++)
        pf[u] = *(const i32x4*)(Wt2 + (size_t)(tap+1)*16384 + (u*256+tid)*8);
    }
    // per-rt im2col source addresses for this tap
    int dx = tap/3 - 1, dy = tap%3 - 1;
    int addrA[4];
    #pragma unroll
    for (int rt=0;rt<4;rt++){
      int row = (wv*4+rt)*16 + lr;       // 0..255
      int pix = row % 81;
      int px = pix/9, py = pix%9;
      int px2 = px + dx, py2 = py + dy;
      bool valid = (row < 243) && ((unsigned)px2 < 9u) && ((unsigned)py2 < 9u);
      int nrow = (row - pix) + px2*9 + py2;
      addrA[rt] = valid ? (nrow*528 + lq*16) : (ZROW + lq*16);
    }
    __syncthreads();   // BL visible, prev tap's readers done earlier

    #pragma unroll
    for (int chunk=0; chunk<4; chunk++){
      bf16x8 b0[4], b1[4], a0[4], a1[4];
      #pragma unroll
      for (int j=0;j<4;j++){
        b0[j] = *(const bf16x8*)(smem + bB + j*1024 + (chunk*2  )*4096);
        b1[j] = *(const bf16x8*)(smem + bB + j*1024 + (chunk*2+1)*4096);
      }
      #pragma unroll
      for (int rt=0;rt<4;rt++){
        a0[rt] = *(const bf16x8*)(smem + addrA[rt] + chunk*128);
        a1[rt] = *(const bf16x8*)(smem + addrA[rt] + chunk*128 + 64);
      }
      #pragma unroll
      for (int rt=0;rt<4;rt++)
        #pragma unroll
        for (int j=0;j<4;j++)
          acc[rt][j] = __builtin_amdgcn_mfma_f32_16x16x32_bf16(a0[rt], b0[j], acc[rt][j], 0, 0, 0);
      #pragma unroll
      for (int rt=0;rt<4;rt++)
        #pragma unroll
        for (int j=0;j<4;j++)
          acc[rt][j] = __builtin_amdgcn_mfma_f32_16x16x32_bf16(a1[rt], b1[j], acc[rt][j], 0, 0, 0);
    }
    __syncthreads();   // readers done before next tap's BL overwrite
  }

  // epilogue: bias (BN folded) + ReLU + spiral scatter + pos_emb
  float t2c[4];
  #pragma unroll
  for (int j=0;j<4;j++){
    int col = j*16 + lr;
    float s2 = g2[col]*rsqrtf(v2[col]+1e-5f);
    t2c[j] = (b2c[col]-m2[col])*s2 + be2[col];
  }
  #pragma unroll
  for (int rt=0;rt<4;rt++){
    #pragma unroll
    for (int e=0;e<4;e++){
      int row = (wv*4+rt)*16 + lq*4 + e;
      if (row < 243 && grow0 + row < 331776){
        int pix = row % 81;
        int img = img0 + row/81;
        int tsp = spiral_t(pix);
        float* dst = stok + ((size_t)img*81 + tsp)*64;
        const float* pe = pos_emb + (1+tsp)*64;
        #pragma unroll
        for (int j=0;j<4;j++){
          int col = j*16 + lr;
          dst[col] = fmaxf(acc[rt][j][e] + t2c[j], 0.f) + pe[col];
        }
      }
    }
  }
}

// ---------------- LN1 + tsum + SToken squeeze -> xn bf16, tsum f32, sqs f32
__global__ __launch_bounds__(256) void k_ln(const float* __restrict__ stok,
    const float* __restrict__ pos_emb, const float* __restrict__ cls_tok,
    const float* __restrict__ ln1_g, const float* __restrict__ ln1_b,
    const float* __restrict__ Wst, const float* __restrict__ bst,
    const float* __restrict__ bias_st,
    u16* __restrict__ xn, float* __restrict__ tsum, float* __restrict__ sqs){
  __shared__ float pt[2][4][64];
  __shared__ float xs[64];
  __shared__ float sqp[4][64];
  int b = blockIdx.x, tid = threadIdx.x;
  int wv = tid >> 6, d = tid & 63;
  const float* sb = stok + (size_t)b*81*64;
  float lg = ln1_g[d], lb = ln1_b[d];
  float ptok = 0.f, pxn = 0.f;
  for (int t = wv; t < 82; t += 4){
    float xv = (t==0) ? (cls_tok[d] + pos_emb[d]) : sb[(t-1)*64 + d];
    float s1 = xv, s2v = xv*xv;
    #pragma unroll
    for (int off=32; off>0; off>>=1){ s1 += __shfl_xor(s1, off, 64); s2v += __shfl_xor(s2v, off, 64); }
    float mean = s1 * (1.f/64.f);
    float var  = s2v*(1.f/64.f) - mean*mean;
    float xnv = (xv - mean) * rsqrtf(var + 1e-5f) * lg + lb;
    xn[((size_t)b*82 + t)*64 + d] = f2bf(xnv);
    ptok += xv; pxn += xnv;
  }
  pt[0][wv][d] = ptok; pt[1][wv][d] = pxn;
  __syncthreads();
  if (tid < 64){
    tsum[b*64 + d] = pt[0][0][d]+pt[0][1][d]+pt[0][2][d]+pt[0][3][d];
    xs[d] = (pt[1][0][d]+pt[1][1][d]+pt[1][2][d]+pt[1][3][d]) * (1.f/82.f);
  }
  __syncthreads();
  {
    float a = 0.f;
    int k0 = wv*16;
    #pragma unroll
    for (int k=0;k<16;k++) a = fmaf(xs[k0+k], Wst[(k0+k)*64+d], a);
    sqp[wv][d] = a;
  }
  __syncthreads();
  if (tid < 64){
    float a = sqp[0][d]+sqp[1][d]+sqp[2][d]+sqp[3][d] + bst[d];
    a = fmaxf(a, 0.f);
    a = 1.f/(1.f + __expf(-a));
    sqs[b*64 + d] = a + bias_st[d];
  }
}

// ---------------- batched GEMM xn@[Wb|Wc|Wd] (M=335872,N=192,K=64) + fused S6 prep
__global__ __launch_bounds__(256, 1) void k_bcd(const u16* __restrict__ xn,
    const float* __restrict__ Wb, const float* __restrict__ Wc, const float* __restrict__ Wd,
    const float* __restrict__ bbv, const float* __restrict__ bcv,
    const float* __restrict__ bdv,
    const float* __restrict__ delta_p, const float* __restrict__ A_p,
    u16* __restrict__ Ax, float* __restrict__ Bxx, u16* __restrict__ Cx){
  __shared__ char At[16384];   // 128 rows x 128B, XOR-swizzled (byte ^ ((row&7)<<4))
  int tid = threadIdx.x;
  int wv = tid >> 6, ln = tid & 63;
  int lq = ln >> 4, lr = ln & 15;
  size_t r0 = (size_t)blockIdx.x * 128;

  // stage A tile (swizzled)
  {
    int row = tid >> 1, hh = tid & 1;
    const char* src = (const char*)xn + (r0 + row)*128 + hh*64;
    #pragma unroll
    for (int c=0;c<4;c++){
      i32x4 v = *(const i32x4*)(src + c*16);
      *(i32x4*)(At + row*128 + ((hh*64 + c*16) ^ ((row&7)<<4))) = v;
    }
  }

  // B fragments from global f32 weights: element (k, c) = W[k*64 + (c&63)]
  bf16x8 bfr[2][12];
  #pragma unroll
  for (int kk=0;kk<2;kk++)
    #pragma unroll
    for (int j=0;j<12;j++){
      int c = j*16 + lr;
      const float* W = (c < 64) ? Wb : ((c < 128) ? Wc : Wd);
      int cc = c & 63;
      int k0 = kk*32 + lq*8;
      bf16x8 f;
      #pragma unroll
      for (int e=0;e<8;e++) f[e] = (short)f2bf(W[(k0+e)*64 + cc]);
      bfr[kk][j] = f;
    }
  __syncthreads();

  f32x4 acc[2][12];
  #pragma unroll
  for (int i=0;i<2;i++)
    #pragma unroll
    for (int j=0;j<12;j++) acc[i][j] = (f32x4){0.f,0.f,0.f,0.f};

  #pragma unroll
  for (int kk=0;kk<2;kk++){
    bf16x8 afr[2];
    #pragma unroll
    for (int i=0;i<2;i++){
      int row = wv*32 + i*16 + lr;
      afr[i] = *(const bf16x8*)(At + row*128 + ((kk*64 + lq*16) ^ ((row&7)<<4)));
    }
    #pragma unroll
    for (int i=0;i<2;i++)
      #pragma unroll
      for (int j=0;j<12;j++)
        acc[i][j] = __builtin_amdgcn_mfma_f32_16x16x32_bf16(afr[i], bfr[kk][j], acc[i][j], 0, 0, 0);
  }

  // epilogue: lane holds (B0, C, Draw) for dim d = j*16+lr at j, j+4, j+8
  #pragma unroll
  for (int i=0;i<2;i++){
    #pragma unroll
    for (int e=0;e<4;e++){
      int row = wv*32 + i*16 + lq*4 + e;
      unsigned rr = (unsigned)(r0 + row);
      unsigned t = rr % 82u;
      #pragma unroll
      for (int j=0;j<4;j++){
        int d = j*16 + lr;
        float B0 = acc[i][j][e]   + bbv[d];
        float Cv = acc[i][j+4][e] + bcv[d];
        float Dr = acc[i][j+8][e] + bdv[d] + delta_p[t*64+d];
        float D  = 1.f/(1.f + __expf(-Dr));
        int byte = j*32 + lr*2;
        float xv = bf2f(*(const u16*)(At + row*128 + (byte ^ ((row&7)<<4))));
        size_t o = (size_t)rr*64 + d;
        Ax[o]  = f2bf(D * A_p[t*64+d]);
        Bxx[o] = D * B0 * xv;
        Cx[o]  = f2bf(Cv);
      }
    }
  }
}

// ---------------- scan + pool + LN2 + MLP (wave per batch, lane per dim)
__global__ __launch_bounds__(256) void k_scan(const u16* __restrict__ xn,
    const u16* __restrict__ Ax, const float* __restrict__ Bxx, const u16* __restrict__ Cx,
    const float* __restrict__ tsum, const float* __restrict__ sqs,
    const float* __restrict__ ln2_g, const float* __restrict__ ln2_b,
    const float* __restrict__ Wm1, const float* __restrict__ bm1,
    const float* __restrict__ Wm2, const float* __restrict__ bm2,
    float* __restrict__ out){
  int tid = threadIdx.x, wv = tid >> 6, d = tid & 63;
  int b = blockIdx.x*4 + wv;
  float sq = sqs[b*64 + d];
  float s = 0.f, racc = 0.f;
  size_t base = (size_t)b*82*64 + d;
  #pragma unroll 2
  for (int t = 0; t < 82; t++){
    float a  = bf2f(Ax[base]);
    float bx = Bxx[base];
    float c  = bf2f(Cx[base]);
    float xv = bf2f(xn[base]);
    s = fmaf(a, s, bx);
    float o = fmaf(c, s, sq*xv);
    float z = 1.f/(1.f + __expf(-xv));
    racc = fmaf(o, z, racc);
    base += 64;
  }
  float pooled = (tsum[b*64 + d] + racc) * (1.f/82.f);
  float s1 = pooled, s2v = pooled*pooled;
  #pragma unroll
  for (int off=32; off>0; off>>=1){ s1 += __shfl_xor(s1, off, 64); s2v += __shfl_xor(s2v, off, 64); }
  float mean = s1*(1.f/64.f), var = s2v*(1.f/64.f) - mean*mean;
  float yn = (pooled - mean)*rsqrtf(var + 1e-5f)*ln2_g[d] + ln2_b[d];
  float a1 = bm1[d];
  for (int k=0;k<64;k++) a1 = fmaf(__shfl(yn, k, 64), Wm1[k*64+d], a1);
  float hg = 0.5f*a1*(1.f + erff(a1*0.70710678118654752f));
  float a2 = bm2[d];
  for (int k=0;k<64;k++) a2 = fmaf(__shfl(hg, k, 64), Wm2[k*64+d], a2);
  out[b*64 + d] = pooled + a2;
}

extern "C" void kernel_launch(void* const* d_in, const int* in_sizes, int n_in,
                              void* d_out, int out_size, void* d_ws, size_t ws_size,
                              hipStream_t stream){
  const float* x       = (const float*)d_in[0];
  const float* w3      = (const float*)d_in[1];
  const float* b3      = (const float*)d_in[2];
  const float* g3      = (const float*)d_in[3];
  const float* be3     = (const float*)d_in[4];
  const float* m3      = (const float*)d_in[5];
  const float* v3      = (const float*)d_in[6];
  const float* w2c     = (const float*)d_in[7];
  const float* b2c     = (const float*)d_in[8];
  const float* g2      = (const float*)d_in[9];
  const float* be2     = (const float*)d_in[10];
  const float* m2      = (const float*)d_in[11];
  const float* v2      = (const float*)d_in[12];
  const float* pos_emb = (const float*)d_in[13];
  const float* cls_tok = (const float*)d_in[14];
  const float* ln1_g   = (const float*)d_in[15];
  const float* ln1_b   = (const float*)d_in[16];
  const float* Wb      = (const float*)d_in[17];
  const float* bbv     = (const float*)d_in[18];
  const float* Wc      = (const float*)d_in[19];
  const float* bc      = (const float*)d_in[20];
  const float* Wd      = (const float*)d_in[21];
  const float* bd      = (const float*)d_in[22];
  const float* delta_p = (const float*)d_in[23];
  const float* A_p     = (const float*)d_in[24];
  const float* Wst     = (const float*)d_in[25];
  const float* bst     = (const float*)d_in[26];
  const float* bias_st = (const float*)d_in[27];
  const float* ln2_g   = (const float*)d_in[28];
  const float* ln2_b   = (const float*)d_in[29];
  const float* Wm1     = (const float*)d_in[30];
  const float* bm1     = (const float*)d_in[31];
  const float* Wm2     = (const float*)d_in[32];
  const float* bm2     = (const float*)d_in[33];

  // workspace layout (bytes), peak = 244,506,624:
  //   phase A: h1 [0,159252480) | Wt2 [159252480,159547392) | stok [159571968,244506624)
  //   phase B overlays (writer strictly precedes all readers):
  //     xn   [0,         42991616)  | Ax [42991616,85983232) | Cx [85983232,128974848)
  //     tsum [128974848,130023424)  | sqs [130023424,131072000)
  //     Bxx  [131072000,217055232)  over dead h1-tail + dead Wt2 + dead stok-head
  char* ws = (char*)d_ws;
  u16*   h1   = (u16*)ws;
  u16*   Wt2  = (u16*)(ws + 159252480);
  float* stok = (float*)(ws + 159571968);
  u16*   xnb  = (u16*)ws;
  u16*   Ax   = (u16*)(ws + 42991616);
  u16*   Cx   = (u16*)(ws + 85983232);
  float* tsum = (float*)(ws + 128974848);
  float* sqs  = (float*)(ws + 130023424);
  float* Bxx  = (float*)(ws + 131072000);

  k_wt    <<<576,  256, 0, stream>>>(w2c, g2, v2, Wt2);
  k_conv3d<<<4096, 256, 0, stream>>>(x, w3, b3, g3, be3, m3, v3, h1);
  k_conv2d<<<1366, 256, 0, stream>>>(h1, Wt2, b2c, g2, be2, m2, v2, pos_emb, stok);
  k_ln    <<<4096, 256, 0, stream>>>(stok, pos_emb, cls_tok, ln1_g, ln1_b,
                                     Wst, bst, bias_st, xnb, tsum, sqs);
  k_bcd   <<<2624, 256, 0, stream>>>(xnb, Wb, Wc, Wd, bbv, bc, bd, delta_p, A_p,
                                     Ax, Bxx, Cx);
  k_scan  <<<1024, 256, 0, stream>>>(xnb, Ax, Bxx, Cx, tsum, sqs,
                                     ln2_g, ln2_b, Wm1, bm1, Wm2, bm2, (float*)d_out);
}